// Round 2
// baseline (248.667 us; speedup 1.0000x reference)
//
#include <hip/hip_runtime.h>
#include <stdint.h>

typedef __attribute__((ext_vector_type(4))) float float4v;

#define D 4096
#define R 16
#define NBL 256   // batch_size_large
#define NBS 256   // batch_size_small

// One block per OUTPUT row (512 blocks). Output row o < 256 sums input rows
// 4o..4o+3; o >= 256 takes input row o+768. Deterministic, no atomics.
// All data float32 (harness promotes the reference's float16 to f32).
__global__ __launch_bounds__(256) void lora_seg_kernel(
    const float* __restrict__ x,
    const float* __restrict__ A,
    const float* __restrict__ B,
    const int* __restrict__ xids,
    const int* __restrict__ wids,
    float* __restrict__ out)
{
    const int o = blockIdx.x;        // 0..511
    const int t = threadIdx.x;       // 0..255
    const int lane = t & 63;
    const int wave = t >> 6;

    int b0, nrows;
    if (o < NBL) { b0 = o * 4; nrows = 4; }
    else         { b0 = o + 768; nrows = 1; }

    __shared__ float hsh[4][R];

    // y accumulator: thread t owns d = 4*t + 1024*c (+j), c in 0..3, j in 0..3
    float acc[16];
    #pragma unroll
    for (int i = 0; i < 16; ++i) acc[i] = 0.f;

    for (int rr = 0; rr < nrows; ++rr) {
        const int b = b0 + rr;
        const int xid = xids[b];
        const int wid = wids[b];
        const float* xrow = x + (size_t)xid * D;
        const float* Amat = A + (size_t)wid * D * R;   // [D][R], r contiguous
        const float* Bmat = B + (size_t)wid * R * D;   // [R][D], d contiguous

        // ---- phase 1: h[r] = sum_d x[d] * A[d][r] ----
        float hp[R];
        #pragma unroll
        for (int r = 0; r < R; ++r) hp[r] = 0.f;

        #pragma unroll
        for (int c = 0; c < 4; ++c) {
            const int dbase = 4 * t + 1024 * c;
            const float4v xv = *(const float4v*)(xrow + dbase);
            #pragma unroll
            for (int j = 0; j < 4; ++j) {
                const float xd = xv[j];
                const float4v* ar = (const float4v*)(Amat + (size_t)(dbase + j) * R);
                #pragma unroll
                for (int q = 0; q < 4; ++q) {
                    const float4v av = ar[q];
                    #pragma unroll
                    for (int r = 0; r < 4; ++r) hp[q * 4 + r] += xd * av[r];
                }
            }
        }

        // wave64 shuffle reduce, then cross-wave combine via LDS
        #pragma unroll
        for (int r = 0; r < R; ++r) {
            float v = hp[r];
            #pragma unroll
            for (int off = 32; off > 0; off >>= 1)
                v += __shfl_xor(v, off, 64);
            if (lane == 0) hsh[wave][r] = v;
        }
        __syncthreads();

        float h[R];
        #pragma unroll
        for (int r = 0; r < R; ++r)
            h[r] = hsh[0][r] + hsh[1][r] + hsh[2][r] + hsh[3][r];
        __syncthreads();  // protect hsh before next row overwrites it

        // ---- phase 2: acc[d] += sum_r h[r] * B[r][d] ----
        #pragma unroll
        for (int r = 0; r < R; ++r) {
            const float hr = h[r];
            const float* br = Bmat + (size_t)r * D;
            #pragma unroll
            for (int c = 0; c < 4; ++c) {
                const int dbase = 4 * t + 1024 * c;
                const float4v bv = *(const float4v*)(br + dbase);
                #pragma unroll
                for (int j = 0; j < 4; ++j)
                    acc[c * 4 + j] += hr * bv[j];
            }
        }
    }

    // ---- epilogue: out = 2 * acc ----
    float* orow = out + (size_t)o * D;
    #pragma unroll
    for (int c = 0; c < 4; ++c) {
        const int dbase = 4 * t + 1024 * c;
        float4v ov;
        #pragma unroll
        for (int j = 0; j < 4; ++j) ov[j] = 2.0f * acc[c * 4 + j];
        *(float4v*)(orow + dbase) = ov;
    }
}

extern "C" void kernel_launch(void* const* d_in, const int* in_sizes, int n_in,
                              void* d_out, int out_size, void* d_ws, size_t ws_size,
                              hipStream_t stream) {
    const float* x    = (const float*)d_in[0];
    const float* A    = (const float*)d_in[1];
    const float* B    = (const float*)d_in[2];
    const int*   xids = (const int*)d_in[3];
    const int*   wids = (const int*)d_in[4];
    float*       out  = (float*)d_out;

    hipLaunchKernelGGL(lora_seg_kernel, dim3(512), dim3(256), 0, stream,
                       x, A, B, xids, wids, out);
}

// Round 3
// 226.106 us; speedup vs baseline: 1.0998x; 1.0998x over previous
//
#include <hip/hip_runtime.h>
#include <stdint.h>

typedef __attribute__((ext_vector_type(4))) float float4v;

#define D 4096
#define R 16
#define NW 192     // N_SPLIT adapters
#define LB 1280    // lora rows
#define NBL 256
#define NBS 256
#define NQ 4       // d-quarter splits
#define DQ 1024    // D / NQ

// ---------------- K0: bucket rows by wid ----------------
__global__ __launch_bounds__(256) void bucket_kernel(
    const int* __restrict__ wids,
    int* __restrict__ bucket,   // [LB]
    int* __restrict__ offs)     // [NW+1]
{
    __shared__ int cnt[NW], sc[NW], cur[NW];
    const int t = threadIdx.x;
    if (t < NW) cnt[t] = 0;
    __syncthreads();
    for (int i = t; i < LB; i += 256) atomicAdd(&cnt[wids[i]], 1);
    __syncthreads();
    if (t < NW) sc[t] = cnt[t];
    __syncthreads();
    for (int s = 1; s < NW; s <<= 1) {
        int v = 0;
        if (t < NW && t >= s) v = sc[t - s];
        __syncthreads();
        if (t < NW) sc[t] += v;
        __syncthreads();
    }
    if (t < NW) { int e = sc[t] - cnt[t]; cur[t] = e; offs[t] = e; }
    if (t == 0) offs[NW] = LB;
    __syncthreads();
    for (int i = t; i < LB; i += 256) {
        int w = wids[i];
        int p = atomicAdd(&cur[w], 1);
        bucket[p] = i;
    }
}

// ---------------- K1: h_part[q][b][16] = x[xid] . A[wid] (d-quarter q) ----
__global__ __launch_bounds__(256) void h_kernel(
    const float* __restrict__ x,
    const float* __restrict__ A,
    const int* __restrict__ xids,
    const int* __restrict__ bucket,
    const int* __restrict__ offs,
    float* __restrict__ hpart)  // [NQ][LB][R]
{
    const int w = blockIdx.x >> 2;
    const int q = blockIdx.x & 3;
    const int t = threadIdx.x;
    const int lane = t & 63;
    const int wave = t >> 6;

    const int start = offs[w], end = offs[w + 1];
    const float* Aq = A + (size_t)w * D * R + (size_t)q * DQ * R;

    for (int i = start + wave; i < end; i += 4) {
        const int b = bucket[i];
        const int xid = xids[b];
        const float* xr = x + (size_t)xid * D + q * DQ;

        float hp[R];
        #pragma unroll
        for (int r = 0; r < R; ++r) hp[r] = 0.f;

        #pragma unroll
        for (int j = 0; j < 4; ++j) {
            const int d0 = j * 256 + lane * 4;
            const float4v xv = *(const float4v*)(xr + d0);
            #pragma unroll
            for (int k = 0; k < 4; ++k) {
                const float xd = xv[k];
                const float4v* ar = (const float4v*)(Aq + (size_t)(d0 + k) * R);
                #pragma unroll
                for (int qq = 0; qq < 4; ++qq) {
                    const float4v av = ar[qq];
                    #pragma unroll
                    for (int r = 0; r < 4; ++r) hp[qq * 4 + r] += xd * av[r];
                }
            }
        }

        // butterfly reduce each of the 16 partials across 64 lanes
        #pragma unroll
        for (int r = 0; r < R; ++r) {
            float v = hp[r];
            #pragma unroll
            for (int off = 32; off > 0; off >>= 1)
                v += __shfl_xor(v, off, 64);
            hp[r] = v;
        }
        if (lane == 0) {
            float* hout = hpart + ((size_t)q * LB + b) * R;
            float4v v0 = {hp[0], hp[1], hp[2], hp[3]};
            float4v v1 = {hp[4], hp[5], hp[6], hp[7]};
            float4v v2 = {hp[8], hp[9], hp[10], hp[11]};
            float4v v3 = {hp[12], hp[13], hp[14], hp[15]};
            *(float4v*)(hout + 0)  = v0;
            *(float4v*)(hout + 4)  = v1;
            *(float4v*)(hout + 8)  = v2;
            *(float4v*)(hout + 12) = v3;
        }
    }
}

// ---------------- K2: y = 2*h.B, scatter into out ----------------
__global__ __launch_bounds__(256) void y_kernel(
    const float* __restrict__ B,
    const int* __restrict__ bucket,
    const int* __restrict__ offs,
    const float* __restrict__ hpart,
    float* __restrict__ out)
{
    const int w = blockIdx.x >> 2;
    const int q = blockIdx.x & 3;
    const int t = threadIdx.x;
    const int lane = t & 63;
    const int wave = t >> 6;

    const int start = offs[w], end = offs[w + 1];
    const float* Bq = B + (size_t)w * R * D + q * DQ;

    for (int i = start + wave; i < end; i += 4) {
        const int b = bucket[i];

        // gather h[16] = sum over the 4 quarter-parts
        float hv = 0.f;
        if (lane < R) {
            #pragma unroll
            for (int p = 0; p < NQ; ++p)
                hv += hpart[((size_t)p * LB + b) * R + lane];
        }
        float h[R];
        #pragma unroll
        for (int r = 0; r < R; ++r) h[r] = __shfl(hv, r, 64);

        const int seg = (b < NBL * 4) ? (b >> 2) : (NBL + (b - NBL * 4));
        float* orow = out + (size_t)seg * D + q * DQ;
        const bool shared_seg = (b < NBL * 4);

        #pragma unroll
        for (int j = 0; j < 4; ++j) {
            const int d0 = j * 256 + lane * 4;
            float4v acc = {0.f, 0.f, 0.f, 0.f};
            #pragma unroll
            for (int r = 0; r < R; ++r) {
                const float4v bv = *(const float4v*)(Bq + (size_t)r * D + d0);
                #pragma unroll
                for (int k = 0; k < 4; ++k) acc[k] += h[r] * bv[k];
            }
            #pragma unroll
            for (int k = 0; k < 4; ++k) acc[k] *= 2.0f;
            if (shared_seg) {
                #pragma unroll
                for (int k = 0; k < 4; ++k)
                    atomicAdd(orow + d0 + k, acc[k]);
            } else {
                *(float4v*)(orow + d0) = acc;
            }
        }
    }
}

extern "C" void kernel_launch(void* const* d_in, const int* in_sizes, int n_in,
                              void* d_out, int out_size, void* d_ws, size_t ws_size,
                              hipStream_t stream) {
    const float* x    = (const float*)d_in[0];
    const float* A    = (const float*)d_in[1];
    const float* B    = (const float*)d_in[2];
    const int*   xids = (const int*)d_in[3];
    const int*   wids = (const int*)d_in[4];
    float*       out  = (float*)d_out;

    // ws layout: bucket[LB] ints | offs[NW+1] ints | pad | hpart[NQ][LB][R] floats
    int*   bucket = (int*)d_ws;
    int*   offs   = bucket + LB;
    float* hpart  = (float*)(((uintptr_t)(offs + NW + 1) + 255) & ~(uintptr_t)255);

    hipMemsetAsync(out, 0, (size_t)(NBL + NBS) * D * sizeof(float), stream);

    hipLaunchKernelGGL(bucket_kernel, dim3(1), dim3(256), 0, stream,
                       wids, bucket, offs);
    hipLaunchKernelGGL(h_kernel, dim3(NW * NQ), dim3(256), 0, stream,
                       x, A, xids, bucket, offs, hpart);
    hipLaunchKernelGGL(y_kernel, dim3(NW * NQ), dim3(256), 0, stream,
                       B, bucket, offs, hpart, out);
}

// Round 4
// 168.862 us; speedup vs baseline: 1.4726x; 1.3390x over previous
//
#include <hip/hip_runtime.h>
#include <stdint.h>

typedef __attribute__((ext_vector_type(4))) float float4v;
typedef __attribute__((ext_vector_type(2))) float float2v;

#define D 4096
#define R 16
#define NW 192     // adapters
#define LB 1280    // lora rows
#define NBL 256
#define NE 8       // d-eighths per adapter (block granularity)
#define DE 512     // D / NE
#define NP 32      // h parts (one per 128-d wave slice)
#define DS 128     // slice width (per wave)
#define MAXB 128   // max bucket size (actual ~15; 128 is deep safety)

// ---------------- K1: hpart[b][p][r] = partial x.A over 128-d slice p ------
// Block (w,e): 4 waves own slices p = 4e..4e+3. Each wave keeps its 32 A
// floats in registers (A fetched from HBM exactly once), loops bucket rows.
__global__ __launch_bounds__(256) void h_kernel(
    const float* __restrict__ x,
    const float* __restrict__ A,
    const int* __restrict__ xids,
    const int* __restrict__ wids,
    float* __restrict__ hpart)   // [LB][NP][R]
{
    const int w = blockIdx.x >> 3;
    const int e = blockIdx.x & 7;
    const int t = threadIdx.x;

    __shared__ int list[MAXB];
    __shared__ int cnt;
    if (t == 0) cnt = 0;
    __syncthreads();
    for (int i = t; i < LB; i += 256)
        if (wids[i] == w) { int q = atomicAdd(&cnt, 1); if (q < MAXB) list[q] = i; }
    __syncthreads();
    int n = cnt; if (n > MAXB) n = MAXB;
    if (n == 0) return;

    const int lane = t & 63;
    const int wave = t >> 6;
    const int p = e * 4 + wave;                 // slice id 0..31

    // A slice into registers: a[k][c] = A[w][d][r], d = p*128+(lane>>2)+16k,
    // r = 4*(lane&3)+c. Loads are fully coalesced (wave covers 8KB contig).
    const float4v* af = (const float4v*)(A + (size_t)w * D * R + (size_t)p * DS * R);
    float4v a[8];
    #pragma unroll
    for (int k = 0; k < 8; ++k) a[k] = af[lane + 64 * k];

    const int dbase = p * DS + (lane >> 2);

    for (int i = 0; i < n; ++i) {
        const int b = list[i];
        const int xid = xids[b];
        const float* xr = x + (size_t)xid * D + dbase;

        float h0 = 0.f, h1 = 0.f, h2 = 0.f, h3 = 0.f;
        #pragma unroll
        for (int k = 0; k < 8; ++k) {
            const float xd = xr[16 * k];        // quad-broadcast, 1 line/instr
            h0 += xd * a[k][0];
            h1 += xd * a[k][1];
            h2 += xd * a[k][2];
            h3 += xd * a[k][3];
        }
        // reduce each r-class (lanes with equal lane&3) over 16 lanes
        #pragma unroll
        for (int off = 4; off <= 32; off <<= 1) {
            h0 += __shfl_xor(h0, off, 64);
            h1 += __shfl_xor(h1, off, 64);
            h2 += __shfl_xor(h2, off, 64);
            h3 += __shfl_xor(h3, off, 64);
        }
        if (lane < 4) {                         // lane L holds r = 4L..4L+3
            float4v hv = {h0, h1, h2, h3};
            *(float4v*)(hpart + ((size_t)b * NP + p) * R + 4 * lane) = hv;
        }
    }
}

// ---------------- K2: y = 2*h.B, scatter/accumulate into out ---------------
// Block (w,e): thread owns d-pair d = e*512+2t, keeps B[r][d..d+1] (32 floats)
// in registers (B fetched from HBM exactly once). Rows loop: 32 FMA + 2 writes.
__global__ __launch_bounds__(256) void y_kernel(
    const float* __restrict__ B,
    const int* __restrict__ wids,
    const float* __restrict__ hpart,
    float* __restrict__ out)
{
    const int w = blockIdx.x >> 3;
    const int e = blockIdx.x & 7;
    const int t = threadIdx.x;

    __shared__ int list[MAXB];
    __shared__ int cnt;
    __shared__ float hl[MAXB][R];
    if (t == 0) cnt = 0;
    __syncthreads();
    for (int i = t; i < LB; i += 256)
        if (wids[i] == w) { int q = atomicAdd(&cnt, 1); if (q < MAXB) list[q] = i; }
    __syncthreads();
    int n = cnt; if (n > MAXB) n = MAXB;
    if (n == 0) return;

    // B registers (coalesced per-r float2 loads)
    const float* Bw = B + (size_t)w * R * D + e * DE + 2 * t;
    float2v breg[R];
    #pragma unroll
    for (int r = 0; r < R; ++r) breg[r] = *(const float2v*)(Bw + (size_t)r * D);

    // h sums for all bucket rows -> LDS
    for (int idx = t; idx < n * R; idx += 256) {
        const int i = idx >> 4, r = idx & 15;
        const float* hp = hpart + (size_t)list[i] * NP * R + r;
        float s = 0.f;
        #pragma unroll
        for (int p = 0; p < NP; ++p) s += hp[p * R];
        hl[i][r] = s;
    }
    __syncthreads();

    const int dcol = e * DE + 2 * t;

    for (int i = 0; i < n; ++i) {
        const int b = list[i];
        float h[R];
        #pragma unroll
        for (int r = 0; r < R; ++r) h[r] = hl[i][r];   // LDS broadcast

        float a0 = 0.f, a1 = 0.f;
        #pragma unroll
        for (int r = 0; r < R; ++r) {
            a0 += h[r] * breg[r][0];
            a1 += h[r] * breg[r][1];
        }
        a0 *= 2.0f; a1 *= 2.0f;

        if (b < NBL * 4) {
            float* o = out + (size_t)(b >> 2) * D + dcol;
            unsafeAtomicAdd(o, a0);
            unsafeAtomicAdd(o + 1, a1);
        } else {
            float* o = out + (size_t)(NBL + (b - NBL * 4)) * D + dcol;
            float2v v = {a0, a1};
            *(float2v*)o = v;
        }
    }
}

extern "C" void kernel_launch(void* const* d_in, const int* in_sizes, int n_in,
                              void* d_out, int out_size, void* d_ws, size_t ws_size,
                              hipStream_t stream) {
    const float* x    = (const float*)d_in[0];
    const float* A    = (const float*)d_in[1];
    const float* B    = (const float*)d_in[2];
    const int*   xids = (const int*)d_in[3];
    const int*   wids = (const int*)d_in[4];
    float*       out  = (float*)d_out;

    float* hpart = (float*)d_ws;   // [LB][NP][R] = 2.62 MB

    // zero only the shared-segment rows (pass-through rows fully overwritten)
    hipMemsetAsync(out, 0, (size_t)NBL * D * sizeof(float), stream);

    hipLaunchKernelGGL(h_kernel, dim3(NW * NE), dim3(256), 0, stream,
                       x, A, xids, wids, hpart);
    hipLaunchKernelGGL(y_kernel, dim3(NW * NE), dim3(256), 0, stream,
                       B, wids, hpart, out);
}

// Round 5
// 157.312 us; speedup vs baseline: 1.5807x; 1.0734x over previous
//
#include <hip/hip_runtime.h>
#include <stdint.h>

typedef __attribute__((ext_vector_type(4))) float float4v;

#define D 4096
#define R 16
#define NW 192     // adapters
#define LB 1280    // lora rows
#define NBL 256
#define MAXB 32    // max bucket size (actual max ~15-16, binomial(1280,1/192))
#define NWAVE 16   // waves per block

// ---------------- fused: per-adapter A->h->B->y ----------------
// Block w: 16 waves. Phase 1: wave j owns d-slice [256j,256j+256); its A
// sub-tile (64 f32/lane) lives in registers, A read from HBM exactly once.
// Phase 2: thread owns d-quad 4t; B sub-tile (16 float4/thread) in registers,
// B read exactly once. h crosses phases via LDS only. Large-segment rows
// plain-store to ybuf (unique writer), small rows store directly to out.
__global__ __launch_bounds__(1024) void fused_kernel(
    const float* __restrict__ x,
    const float* __restrict__ A,
    const float* __restrict__ B,
    const int* __restrict__ xids,
    const int* __restrict__ wids,
    float* __restrict__ ybuf,   // [NBL*4][D]
    float* __restrict__ out)    // [512][D]
{
    const int w = blockIdx.x;
    const int t = threadIdx.x;
    const int lane = t & 63;
    const int wave = t >> 6;

    __shared__ int list[MAXB];
    __shared__ int xidl[MAXB];
    __shared__ int cnt;
    __shared__ float hws[MAXB][NWAVE][17];  // +1 pad: stride 17 kills bank conflicts
    __shared__ float hl[MAXB][R];

    if (t == 0) cnt = 0;
    __syncthreads();
    for (int i = t; i < LB; i += 1024)
        if (wids[i] == w) { int q = atomicAdd(&cnt, 1); if (q < MAXB) list[q] = i; }
    __syncthreads();
    int n = cnt > MAXB ? MAXB : cnt;
    if (n == 0) return;
    if (t < n) xidl[t] = xids[list[t]];
    __syncthreads();

    // ---- phase 1: h[i][r] = x[xid_i] . A ----
    // lane owns d = 256*wave + (lane>>2) + 16k (k=0..15), r = 4*(lane&3)+c.
    // A load: af[1024*wave + 64k + lane] -> contiguous 1KB per wave ✓
    const float4v* af = (const float4v*)(A + (size_t)w * D * R);
    float4v a[16];
    #pragma unroll
    for (int k = 0; k < 16; ++k) a[k] = af[1024 * wave + 64 * k + lane];

    const int dof = 256 * wave + (lane >> 2);
    for (int i = 0; i < n; ++i) {
        const float* xr = x + (size_t)xidl[i] * D + dof;
        float h0 = 0.f, h1 = 0.f, h2 = 0.f, h3 = 0.f;
        #pragma unroll
        for (int k = 0; k < 16; ++k) {
            const float xd = xr[16 * k];      // quad-broadcast, 64B/line per instr
            h0 += xd * a[k][0];
            h1 += xd * a[k][1];
            h2 += xd * a[k][2];
            h3 += xd * a[k][3];
        }
        // reduce over the 16 lane-groups sharing (lane&3)
        #pragma unroll
        for (int off = 4; off <= 32; off <<= 1) {
            h0 += __shfl_xor(h0, off, 64);
            h1 += __shfl_xor(h1, off, 64);
            h2 += __shfl_xor(h2, off, 64);
            h3 += __shfl_xor(h3, off, 64);
        }
        if (lane < 4) {                        // lane L holds r = 4L..4L+3
            hws[i][wave][4 * lane + 0] = h0;
            hws[i][wave][4 * lane + 1] = h1;
            hws[i][wave][4 * lane + 2] = h2;
            hws[i][wave][4 * lane + 3] = h3;
        }
    }
    __syncthreads();
    for (int idx = t; idx < n * R; idx += 1024) {
        const int i = idx >> 4, r = idx & 15;
        float s = 0.f;
        #pragma unroll
        for (int j = 0; j < NWAVE; ++j) s += hws[i][j][r];
        hl[i][r] = s;
    }
    __syncthreads();

    // ---- phase 2: y = 2*h.B ----
    const float* Bw = B + (size_t)w * R * D + 4 * t;
    float4v breg[R];
    #pragma unroll
    for (int r = 0; r < R; ++r) breg[r] = *(const float4v*)(Bw + (size_t)r * D);

    for (int i = 0; i < n; ++i) {
        const int b = list[i];
        float4v acc = {0.f, 0.f, 0.f, 0.f};
        #pragma unroll
        for (int r = 0; r < R; ++r) {
            const float hr = hl[i][r];         // LDS broadcast
            acc[0] += hr * breg[r][0];
            acc[1] += hr * breg[r][1];
            acc[2] += hr * breg[r][2];
            acc[3] += hr * breg[r][3];
        }
        #pragma unroll
        for (int k = 0; k < 4; ++k) acc[k] *= 2.0f;

        if (b < NBL * 4) {
            *(float4v*)(ybuf + (size_t)b * D + 4 * t) = acc;        // unique writer
        } else {
            *(float4v*)(out + (size_t)(NBL + (b - NBL * 4)) * D + 4 * t) = acc;
        }
    }
}

// ---------------- sum4: out[o] = ybuf[4o]+ybuf[4o+1]+ybuf[4o+2]+ybuf[4o+3] ---
__global__ __launch_bounds__(256) void sum4_kernel(
    const float* __restrict__ ybuf,
    float* __restrict__ out)
{
    const int o = blockIdx.x >> 2;            // 0..255
    const int q = blockIdx.x & 3;             // d-quarter
    const int col = q * 1024 + 4 * threadIdx.x;
    const float* y0 = ybuf + (size_t)(4 * o) * D + col;
    float4v v0 = *(const float4v*)(y0);
    float4v v1 = *(const float4v*)(y0 + D);
    float4v v2 = *(const float4v*)(y0 + 2 * D);
    float4v v3 = *(const float4v*)(y0 + 3 * D);
    float4v s;
    #pragma unroll
    for (int k = 0; k < 4; ++k) s[k] = (v0[k] + v1[k]) + (v2[k] + v3[k]);
    *(float4v*)(out + (size_t)o * D + col) = s;
}

extern "C" void kernel_launch(void* const* d_in, const int* in_sizes, int n_in,
                              void* d_out, int out_size, void* d_ws, size_t ws_size,
                              hipStream_t stream) {
    const float* x    = (const float*)d_in[0];
    const float* A    = (const float*)d_in[1];
    const float* B    = (const float*)d_in[2];
    const int*   xids = (const int*)d_in[3];
    const int*   wids = (const int*)d_in[4];
    float*       out  = (float*)d_out;

    float* ybuf = (float*)d_ws;   // [1024][4096] f32 = 16 MB

    hipLaunchKernelGGL(fused_kernel, dim3(NW), dim3(1024), 0, stream,
                       x, A, B, xids, wids, ybuf, out);
    hipLaunchKernelGGL(sum4_kernel, dim3(NBL * 4), dim3(256), 0, stream,
                       ybuf, out);
}